// Round 1
// baseline (197.862 us; speedup 1.0000x reference)
//
#include <hip/hip_runtime.h>
#include <math.h>

// Problem constants (from reference): B=4, S=2048, DIN=1024, DOUT=1024, E=16, K=2
#define BB    4
#define SS    2048
#define DIN_  1024
#define DOUT_ 1024
#define NE    16
#define KK    2
#define NTOK  (BB * SS)   // 8192 tokens

// ---------------------------------------------------------------------------
// Kernel A: compact the only-needed expert_w columns (j = 0,1) into
// Wc[e][j][d] (contiguous per column) in workspace. 16*2*1024 floats = 128 KB.
// ---------------------------------------------------------------------------
__global__ __launch_bounds__(256) void compact_w_kernel(
    const float* __restrict__ ew,   // [E, DIN, DOUT]
    float* __restrict__ wc)         // [E, K, DIN]
{
    int i = blockIdx.x * 256 + threadIdx.x;   // over NE*KK*DIN = 32768
    if (i >= NE * KK * DIN_) return;
    int d = i & (DIN_ - 1);
    int j = (i >> 10) & 1;
    int e = i >> 11;
    wc[i] = ew[(size_t)e * DIN_ * DOUT_ + (size_t)d * DOUT_ + j];
}

// ---------------------------------------------------------------------------
// Kernel B: one block per token. 256 threads, each owns 4 consecutive d's.
// ---------------------------------------------------------------------------
__global__ __launch_bounds__(256) void moe_token_kernel(
    const float* __restrict__ x,        // [NTOK, DIN]
    const float* __restrict__ gate_w,   // [DIN, E]
    const float* __restrict__ gate_b,   // [E]
    const float* __restrict__ expert_b, // [E, DOUT]
    const float* __restrict__ ebias,    // [E] (routing bias, zeros but honored)
    const float* __restrict__ wc,       // [E, K, DIN] compact columns
    float* __restrict__ out_final,      // [NTOK, DOUT]
    float* __restrict__ out_probs,      // [NTOK, E]
    float* __restrict__ out_idx,        // [NTOK, K] stored as float
    int write_aux)
{
    __shared__ float s_wred[4][16];
    __shared__ float s_ered[4][2];
    __shared__ int   s_e[2];
    __shared__ float s_w[2];
    __shared__ float s_final;

    const int token = blockIdx.x;
    const int t     = threadIdx.x;
    const int lane  = t & 63;
    const int wave  = t >> 6;

    // x row: 256 threads x float4 = 1024 floats, coalesced
    float4 x4 = ((const float4*)(x + (size_t)token * DIN_))[t];
    float xs[4] = {x4.x, x4.y, x4.z, x4.w};

    // ---- gating: partial dots for all 16 experts -------------------------
    float acc[16];
#pragma unroll
    for (int e = 0; e < 16; e++) acc[e] = 0.f;

    const float4* gw4 = (const float4*)gate_w;  // row d = 4 float4s
#pragma unroll
    for (int i = 0; i < 4; i++) {
        int d = 4 * t + i;
        float4 g0 = gw4[d * 4 + 0];
        float4 g1 = gw4[d * 4 + 1];
        float4 g2 = gw4[d * 4 + 2];
        float4 g3 = gw4[d * 4 + 3];
        float xv = xs[i];
        acc[0]  += xv * g0.x; acc[1]  += xv * g0.y; acc[2]  += xv * g0.z; acc[3]  += xv * g0.w;
        acc[4]  += xv * g1.x; acc[5]  += xv * g1.y; acc[6]  += xv * g1.z; acc[7]  += xv * g1.w;
        acc[8]  += xv * g2.x; acc[9]  += xv * g2.y; acc[10] += xv * g2.z; acc[11] += xv * g2.w;
        acc[12] += xv * g3.x; acc[13] += xv * g3.y; acc[14] += xv * g3.z; acc[15] += xv * g3.w;
    }

    // wave-level butterfly reduce each accumulator (wave = 64 lanes)
#pragma unroll
    for (int e = 0; e < 16; e++) {
        float v = acc[e];
#pragma unroll
        for (int m = 32; m >= 1; m >>= 1) v += __shfl_xor(v, m, 64);
        acc[e] = v;
    }
    if (lane == 0) {
#pragma unroll
        for (int e = 0; e < 16; e++) s_wred[wave][e] = acc[e];
    }
    __syncthreads();

    // ---- thread 0: finish gates, sigmoid, top-2, renorm, aux writes ------
    if (t == 0) {
        float probs[16], logit[16];
        for (int e = 0; e < 16; e++) {
            float go = s_wred[0][e] + s_wred[1][e] + s_wred[2][e] + s_wred[3][e]
                       + gate_b[e];
            probs[e] = 1.f / (1.f + expf(-go));
            logit[e] = go + ebias[e];
        }
        // stable top-2 (descending; ties -> lower index, matching lax.top_k)
        int i0 = 0;
        for (int e = 1; e < 16; e++) if (logit[e] > logit[i0]) i0 = e;
        int i1 = -1;
        for (int e = 0; e < 16; e++) {
            if (e == i0) continue;
            if (i1 < 0 || logit[e] > logit[i1]) i1 = e;
        }
        float p0 = probs[i0], p1 = probs[i1];
        float inv = 1.f / (p0 + p1);
        s_e[0] = i0; s_e[1] = i1;
        s_w[0] = p0 * inv; s_w[1] = p1 * inv;
        if (write_aux) {
#pragma unroll
            for (int e = 0; e < 16; e++) out_probs[(size_t)token * NE + e] = probs[e];
            out_idx[(size_t)token * KK + 0] = (float)i0;
            out_idx[(size_t)token * KK + 1] = (float)i1;
        }
    }
    __syncthreads();

    // ---- expert column dots: x . Wc[e0][0][:], x . Wc[e1][1][:] ----------
    int e0 = s_e[0], e1 = s_e[1];
    float4 a4 = ((const float4*)(wc + ((size_t)e0 * KK + 0) * DIN_))[t];
    float4 b4 = ((const float4*)(wc + ((size_t)e1 * KK + 1) * DIN_))[t];
    float g0 = x4.x * a4.x + x4.y * a4.y + x4.z * a4.z + x4.w * a4.w;
    float g1 = x4.x * b4.x + x4.y * b4.y + x4.z * b4.z + x4.w * b4.w;
#pragma unroll
    for (int m = 32; m >= 1; m >>= 1) {
        g0 += __shfl_xor(g0, m, 64);
        g1 += __shfl_xor(g1, m, 64);
    }
    if (lane == 0) { s_ered[wave][0] = g0; s_ered[wave][1] = g1; }
    __syncthreads();

    if (t == 0) {
        float G0 = s_ered[0][0] + s_ered[1][0] + s_ered[2][0] + s_ered[3][0]
                   + expert_b[(size_t)e0 * DOUT_ + 0];
        float G1 = s_ered[0][1] + s_ered[1][1] + s_ered[2][1] + s_ered[3][1]
                   + expert_b[(size_t)e1 * DOUT_ + 1];
        s_final = G0 * s_w[0] + G1 * s_w[1];
    }
    __syncthreads();

    // ---- broadcast scalar over DOUT ---------------------------------------
    float f = s_final;
    ((float4*)(out_final + (size_t)token * DOUT_))[t] = make_float4(f, f, f, f);
}

// ---------------------------------------------------------------------------
extern "C" void kernel_launch(void* const* d_in, const int* in_sizes, int n_in,
                              void* d_out, int out_size, void* d_ws, size_t ws_size,
                              hipStream_t stream) {
    const float* x        = (const float*)d_in[0];
    const float* gate_w   = (const float*)d_in[1];
    const float* gate_b   = (const float*)d_in[2];
    const float* expert_w = (const float*)d_in[3];
    const float* expert_b = (const float*)d_in[4];
    const float* ebias    = (const float*)d_in[5];
    float* out = (float*)d_out;
    float* wc  = (float*)d_ws;   // 128 KB compact expert columns

    compact_w_kernel<<<(NE * KK * DIN_ + 255) / 256, 256, 0, stream>>>(expert_w, wc);

    float* out_final = out;
    float* out_probs = out + (size_t)NTOK * DOUT_;
    float* out_idx   = out_probs + (size_t)NTOK * NE;
    // If the harness only compares final_output, out_size will be smaller;
    // only write aux chunks when the buffer actually holds them.
    int write_aux = (out_size >= NTOK * DOUT_ + NTOK * NE + NTOK * KK) ? 1 : 0;

    moe_token_kernel<<<NTOK, 256, 0, stream>>>(
        x, gate_w, gate_b, expert_b, ebias, wc,
        out_final, out_probs, out_idx, write_aux);
}

// Round 2
// 157.055 us; speedup vs baseline: 1.2598x; 1.2598x over previous
//
#include <hip/hip_runtime.h>
#include <math.h>

// Problem constants: B=4, S=2048, DIN=1024, DOUT=1024, E=16, K=2
#define DIN_  1024
#define DOUT_ 1024
#define NE    16
#define KK    2
#define NTOK  8192

// ws layout: [0, 128KB)  : float4 rec[NTOK] = (e0, e1, w0, w1)
//            [128KB,256KB): float wc[E][K][DIN] compact expert columns

// ---------------------------------------------------------------------------
// Kernel A: compact expert_w columns j=0,1 into Wc[e][j][d]. 128 KB.
// ---------------------------------------------------------------------------
__global__ __launch_bounds__(256) void compact_w_kernel(
    const float* __restrict__ ew,   // [E, DIN, DOUT]
    float* __restrict__ wc)         // [E, K, DIN]
{
    int i = blockIdx.x * 256 + threadIdx.x;   // over NE*KK*DIN = 32768
    if (i >= NE * KK * DIN_) return;
    int d = i & (DIN_ - 1);
    int j = (i >> 10) & 1;
    int e = i >> 11;
    wc[i] = ew[(size_t)e * DIN_ * DOUT_ + (size_t)d * DOUT_ + j];
}

// ---------------------------------------------------------------------------
// Kernel B: gating. Block = 256 threads = 16 tokens x 16 d-segments (64 d ea).
// Each thread keeps all 16 expert partials in registers -> one LDS reduce.
// ---------------------------------------------------------------------------
__global__ __launch_bounds__(256) void gate_kernel(
    const float* __restrict__ x,        // [NTOK, DIN]
    const float* __restrict__ gate_w,   // [DIN, E]
    const float* __restrict__ gate_b,   // [E]
    const float* __restrict__ ebias,    // [E]
    float* __restrict__ out_probs,      // [NTOK, E]
    float* __restrict__ out_idx,        // [NTOK, K] as float
    float4* __restrict__ ws_rec,        // [NTOK]
    int write_aux)
{
    __shared__ float red[NE][16][17];   // [e][seg][tok+pad] ~17.4 KB
    __shared__ float lgt[16 * NE];      // [tok][e]

    const int tid = threadIdx.x;
    const int seg = tid >> 4;           // 0..15
    const int tok = tid & 15;           // 0..15
    const int token = blockIdx.x * 16 + tok;

    const float4* x4  = (const float4*)(x + (size_t)token * DIN_) + seg * 16;
    const float4* gw4 = (const float4*)gate_w;  // row d = 4 float4s

    float acc[NE];
#pragma unroll
    for (int e = 0; e < NE; e++) acc[e] = 0.f;

    for (int i = 0; i < 16; i++) {
        float4 xv = x4[i];
        int d0 = seg * 64 + i * 4;
#pragma unroll
        for (int j = 0; j < 4; j++) {
            int d = d0 + j;
            float xs = (j == 0) ? xv.x : (j == 1) ? xv.y : (j == 2) ? xv.z : xv.w;
            float4 g0 = gw4[d * 4 + 0];
            float4 g1 = gw4[d * 4 + 1];
            float4 g2 = gw4[d * 4 + 2];
            float4 g3 = gw4[d * 4 + 3];
            acc[0]  += xs * g0.x; acc[1]  += xs * g0.y; acc[2]  += xs * g0.z; acc[3]  += xs * g0.w;
            acc[4]  += xs * g1.x; acc[5]  += xs * g1.y; acc[6]  += xs * g1.z; acc[7]  += xs * g1.w;
            acc[8]  += xs * g2.x; acc[9]  += xs * g2.y; acc[10] += xs * g2.z; acc[11] += xs * g2.w;
            acc[12] += xs * g3.x; acc[13] += xs * g3.y; acc[14] += xs * g3.z; acc[15] += xs * g3.w;
        }
    }

#pragma unroll
    for (int e = 0; e < NE; e++) red[e][seg][tok] = acc[e];
    __syncthreads();

    // reduce over segments: thread' = rtok*16 + e
    {
        const int rtok = tid >> 4;
        const int e    = tid & 15;
        float s = 0.f;
#pragma unroll
        for (int sg = 0; sg < 16; sg++) s += red[e][sg][rtok];
        s += gate_b[e];
        float prob = 1.f / (1.f + expf(-s));
        int gtoken = blockIdx.x * 16 + rtok;
        if (write_aux) out_probs[(size_t)gtoken * NE + e] = prob;
        lgt[rtok * NE + e] = s;
    }
    __syncthreads();

    // finalize: threads 0..15, one token each
    if (tid < 16) {
        const int ftok = tid;
        const int gtoken = blockIdx.x * 16 + ftok;
        float go[NE], logit[NE];
#pragma unroll
        for (int e = 0; e < NE; e++) {
            go[e] = lgt[ftok * NE + e];
            logit[e] = go[e] + ebias[e];
        }
        // stable top-2 (descending; ties -> lower index)
        int i0 = 0;
        for (int e = 1; e < NE; e++) if (logit[e] > logit[i0]) i0 = e;
        int i1 = -1;
        for (int e = 0; e < NE; e++) {
            if (e == i0) continue;
            if (i1 < 0 || logit[e] > logit[i1]) i1 = e;
        }
        float p0 = 1.f / (1.f + expf(-go[i0]));
        float p1 = 1.f / (1.f + expf(-go[i1]));
        float inv = 1.f / (p0 + p1);
        if (write_aux) {
            out_idx[(size_t)gtoken * KK + 0] = (float)i0;
            out_idx[(size_t)gtoken * KK + 1] = (float)i1;
        }
        ws_rec[gtoken] = make_float4((float)i0, (float)i1, p0 * inv, p1 * inv);
    }
}

// ---------------------------------------------------------------------------
// Kernel C: expert dots + broadcast. One wave per token, no LDS, no syncs.
// ---------------------------------------------------------------------------
__global__ __launch_bounds__(256) void expert_kernel(
    const float* __restrict__ x,        // [NTOK, DIN]
    const float* __restrict__ wc,       // [E, K, DIN]
    const float* __restrict__ expert_b, // [E, DOUT]
    const float4* __restrict__ ws_rec,  // [NTOK]
    float* __restrict__ out_final)      // [NTOK, DOUT]
{
    const int wave = threadIdx.x >> 6;
    const int lane = threadIdx.x & 63;
    const int token = blockIdx.x * 4 + wave;

    float4 rec = ws_rec[token];
    int e0 = (int)rec.x;
    int e1 = (int)rec.y;

    const float4* xr = (const float4*)(x + (size_t)token * DIN_);
    const float4* w0 = (const float4*)(wc + ((size_t)e0 * KK + 0) * DIN_);
    const float4* w1 = (const float4*)(wc + ((size_t)e1 * KK + 1) * DIN_);

    float g0 = 0.f, g1 = 0.f;
#pragma unroll
    for (int i = 0; i < 4; i++) {
        float4 xv = xr[i * 64 + lane];
        float4 a  = w0[i * 64 + lane];
        float4 b  = w1[i * 64 + lane];
        g0 += xv.x * a.x + xv.y * a.y + xv.z * a.z + xv.w * a.w;
        g1 += xv.x * b.x + xv.y * b.y + xv.z * b.z + xv.w * b.w;
    }
#pragma unroll
    for (int m = 32; m >= 1; m >>= 1) {
        g0 += __shfl_xor(g0, m, 64);
        g1 += __shfl_xor(g1, m, 64);
    }
    float f = rec.z * (g0 + expert_b[(size_t)e0 * DOUT_ + 0])
            + rec.w * (g1 + expert_b[(size_t)e1 * DOUT_ + 1]);
    float4 fv = make_float4(f, f, f, f);
    float4* o4 = (float4*)(out_final + (size_t)token * DOUT_);
#pragma unroll
    for (int i = 0; i < 4; i++) o4[i * 64 + lane] = fv;
}

// ---------------------------------------------------------------------------
extern "C" void kernel_launch(void* const* d_in, const int* in_sizes, int n_in,
                              void* d_out, int out_size, void* d_ws, size_t ws_size,
                              hipStream_t stream) {
    const float* x        = (const float*)d_in[0];
    const float* gate_w   = (const float*)d_in[1];
    const float* gate_b   = (const float*)d_in[2];
    const float* expert_w = (const float*)d_in[3];
    const float* expert_b = (const float*)d_in[4];
    const float* ebias    = (const float*)d_in[5];
    float* out = (float*)d_out;

    float4* ws_rec = (float4*)d_ws;                       // 128 KB
    float*  wc     = (float*)d_ws + (size_t)NTOK * 4;     // 128 KB

    float* out_final = out;
    float* out_probs = out + (size_t)NTOK * DOUT_;
    float* out_idx   = out_probs + (size_t)NTOK * NE;
    int write_aux = (out_size >= NTOK * DOUT_ + NTOK * NE + NTOK * KK) ? 1 : 0;

    compact_w_kernel<<<(NE * KK * DIN_ + 255) / 256, 256, 0, stream>>>(expert_w, wc);
    gate_kernel<<<NTOK / 16, 256, 0, stream>>>(
        x, gate_w, gate_b, ebias, out_probs, out_idx, ws_rec, write_aux);
    expert_kernel<<<NTOK / 4, 256, 0, stream>>>(
        x, wc, expert_b, ws_rec, out_final);
}